// Round 1
// baseline (855.057 us; speedup 1.0000x reference)
//
#include <hip/hip_runtime.h>

#define B_TOK 32768
#define D_IN  256
#define H_LAT 8192
#define TOPK  32
#define MT    64          // rows per block
#define NT    128         // h-cols per chunk
#define NCH   (H_LAT / NT)
#define CAP   144         // candidate pool per row (thr=2.3sigma -> lambda~90)
#define XS    264         // xbf row stride (ushort): 132 dw -> 2-way bank alias (free)
#define DELTA 0.016f      // exact-rescore window; ~8 sigma of bf16-GEMM+pack err (~1.8e-3)

typedef __attribute__((ext_vector_type(4))) float f32x4;
typedef __attribute__((ext_vector_type(8))) short bf16x8;

__device__ __forceinline__ unsigned short f2bf(float f) {   // RNE fp32->bf16
    unsigned u = __float_as_uint(f);
    return (unsigned short)((u + 0x7fffu + ((u >> 16) & 1u)) >> 16);
}
__device__ __forceinline__ float bf2f(unsigned short u) {
    return __uint_as_float((unsigned)u << 16);
}

// Kernel A: W_enc fp32 -> bf16 (+ sum W^2); W_dec fp32 -> bf16 (decoder copy).
__global__ __launch_bounds__(256)
void conv_kernel(const float* __restrict__ W, unsigned short* __restrict__ Wbf,
                 float* __restrict__ s2w, const float* __restrict__ Wd,
                 unsigned short* __restrict__ Wdbf) {
    const int total4 = (H_LAT * D_IN) / 4;
    float acc = 0.0f;
    for (int i = blockIdx.x * blockDim.x + threadIdx.x; i < total4;
         i += gridDim.x * blockDim.x) {
        const float4 v = ((const float4*)W)[i];
        acc += v.x * v.x + v.y * v.y + v.z * v.z + v.w * v.w;
        ushort4 o;
        o.x = f2bf(v.x); o.y = f2bf(v.y); o.z = f2bf(v.z); o.w = f2bf(v.w);
        ((ushort4*)Wbf)[i] = o;
    }
    for (int i = blockIdx.x * blockDim.x + threadIdx.x; i < total4;
         i += gridDim.x * blockDim.x) {
        const float4 v = ((const float4*)Wd)[i];
        ushort4 o;
        o.x = f2bf(v.x); o.y = f2bf(v.y); o.z = f2bf(v.z); o.w = f2bf(v.w);
        ((ushort4*)Wdbf)[i] = o;
    }
#pragma unroll
    for (int off = 32; off > 0; off >>= 1) acc += __shfl_down(acc, off, 64);
    if ((threadIdx.x & 63) == 0) atomicAdd(s2w, acc);
}

// Kernel B: 512 threads, 8 waves in a 2x4 (row-half x col-strip) grid.
// A-in-registers (64 VGPR/wave) barrier-free bf16-MFMA filter -> packed pool ->
// wave rank-count top-64 -> exact fp32 rescore of boundary window -> final
// rank top-32 -> bf16 decoder. 2 blocks/CU = 16 waves/CU.
__global__ __launch_bounds__(512, 4)
void sae_main(const float* __restrict__ x, const float* __restrict__ W_enc,
              const float* __restrict__ b_enc, const float* __restrict__ W_dec,
              const float* __restrict__ b_dec, float* __restrict__ out,
              const unsigned short* __restrict__ Wbf, const float* __restrict__ s2w,
              const unsigned short* __restrict__ Wdbf) {
    __shared__ __align__(16) unsigned short xbf[MT][XS];    // 33792 B; ext overlays post-GEMM
    __shared__ unsigned pool[MT][CAP];                      // 36864 B packed (bf16<<13)|(8191-col)
    __shared__ int   cnt[MT];
    __shared__ float thr[MT];

    const int tid  = threadIdx.x;
    const int row0 = blockIdx.x * MT;
    const int wave = tid >> 6, lane = tid & 63;
    const int l15 = lane & 15, quad = lane >> 4;
    const int wr = wave >> 2;                               // row half   (0..1)
    const int wc = wave & 3;                                // col strip  (0..3)

    if (tid < MT) { cnt[tid] = 0; thr[tid] = 0.0f; }
    __syncthreads();

    // ---- Phase 0: stage (x - b_dec) -> bf16 LDS; per-row sum(x^2) ----
    {
        const int r = tid >> 3, q = tid & 7;                // 8 threads/row, 32 k each
        const float* xr = x + (size_t)(row0 + r) * D_IN + q * 32;
        const float* bd = b_dec + q * 32;
        float s2 = 0.0f;
#pragma unroll
        for (int j = 0; j < 4; ++j) {
            const float4 a = ((const float4*)xr)[2 * j];
            const float4 b = ((const float4*)xr)[2 * j + 1];
            const float4 da = ((const float4*)bd)[2 * j];
            const float4 db = ((const float4*)bd)[2 * j + 1];
            float v[8] = {a.x - da.x, a.y - da.y, a.z - da.z, a.w - da.w,
                          b.x - db.x, b.y - db.y, b.z - db.z, b.w - db.w};
            ushort4 p0, p1;
            p0.x = f2bf(v[0]); p0.y = f2bf(v[1]); p0.z = f2bf(v[2]); p0.w = f2bf(v[3]);
            p1.x = f2bf(v[4]); p1.y = f2bf(v[5]); p1.z = f2bf(v[6]); p1.w = f2bf(v[7]);
#pragma unroll
            for (int e = 0; e < 8; ++e) s2 += v[e] * v[e];
            *(ushort4*)&xbf[r][q * 32 + j * 8]     = p0;
            *(ushort4*)&xbf[r][q * 32 + j * 8 + 4] = p1;
        }
        atomicAdd(&thr[r], s2);
    }
    __syncthreads();
    if (tid < MT) {
        const float s2wm = s2w[0] * (1.0f / ((float)H_LAT * (float)D_IN));
        thr[tid] = 2.3f * sqrtf(s2wm * thr[tid]);
    }
    __syncthreads();

    float thrv[2][4];
#pragma unroll
    for (int mt = 0; mt < 2; ++mt)
#pragma unroll
        for (int qi = 0; qi < 4; ++qi) thrv[mt][qi] = thr[wr * 32 + mt * 16 + quad * 4 + qi];

    // ---- One-time: load this wave's A operand (its row-half) into registers ----
    // Fragment for K-chunk c8: A[m=l15][k=c8*32+quad*8+j], j=0..7. 64 VGPRs.
    bf16x8 areg[2][8];
#pragma unroll
    for (int mt = 0; mt < 2; ++mt)
#pragma unroll
        for (int c8 = 0; c8 < 8; ++c8)
            areg[mt][c8] = *(const bf16x8*)&xbf[wr * 32 + mt * 16 + l15][c8 * 32 + quad * 8];

    // ---- Phase 1: barrier-free, LDS-free MFMA K-loop; wave owns 32-col strip ----
    const int colbase = wc * 32;
    for (int nc = 0; nc < NCH; ++nc) {
        const int h0 = nc * NT;
        // prefetch bias for this strip (in flight during the MFMAs)
        float bv[2];
#pragma unroll
        for (int ct = 0; ct < 2; ++ct) bv[ct] = b_enc[h0 + colbase + ct * 16 + l15];

        f32x4 acc[2][2];
#pragma unroll
        for (int mt = 0; mt < 2; ++mt)
#pragma unroll
            for (int ct = 0; ct < 2; ++ct) acc[mt][ct] = {0.f, 0.f, 0.f, 0.f};

#pragma unroll
        for (int c8 = 0; c8 < 8; ++c8) {
#pragma unroll
            for (int ct = 0; ct < 2; ++ct) {
                const unsigned short* bp =
                    Wbf + (size_t)(h0 + colbase + ct * 16 + l15) * D_IN + c8 * 32 + quad * 8;
                const bf16x8 b = *(const bf16x8*)bp;           // direct from L1/L2
#pragma unroll
                for (int mt = 0; mt < 2; ++mt)
                    acc[mt][ct] = __builtin_amdgcn_mfma_f32_16x16x32_bf16(areg[mt][c8], b, acc[mt][ct], 0, 0, 0);
            }
        }
        // collection (C/D: col=lane&15, row=quad*4+reg); packed 4B entries
#pragma unroll
        for (int ct = 0; ct < 2; ++ct) {
            const int col = h0 + colbase + ct * 16 + l15;
#pragma unroll
            for (int mt = 0; mt < 2; ++mt)
#pragma unroll
                for (int qi = 0; qi < 4; ++qi) {
                    const float v = acc[mt][ct][qi] + bv[ct];
                    if (v > thrv[mt][qi]) {
                        const int r = wr * 32 + mt * 16 + quad * 4 + qi;
                        const int pos = atomicAdd(&cnt[r], 1);
                        if (pos < CAP)
                            pool[r][pos] = ((unsigned)f2bf(v) << 13) | (unsigned)(8191 - col);
                    }
                }
        }
    }
    __syncthreads();    // pools complete; xbf dead -> ext overlays it

    unsigned short* ext_i = (unsigned short*)&xbf[0][0];        // [MT][64] (8 KB)
    float*          ext_v = (float*)((char*)&xbf[0][0] + MT * 64 * 2); // [MT][64] (16 KB)

    // ---- Phase 2: wave rank-count on packed keys -> top-64 (idx + approx val) ----
    {
        const int rbase = wave * 8;
        for (int rr = 0; rr < 8; ++rr) {
            const int r = rbase + rr;
            const int n = min(cnt[r], CAP);
            unsigned p[3]; int rk[3];
            const int S = (n <= 128) ? 2 : 3;                   // wave-uniform
#pragma unroll
            for (int e = 0; e < 3; ++e) {
                const int c = e * 64 + lane;
                p[e] = (c < n) ? pool[r][c] : (unsigned)(c + 1);  // unique tiny sentinels
                rk[e] = 0;
            }
            if (S == 2) {
                for (int s = 0; s < 64; ++s) {
                    const int src = (lane + s) & 63;
                    const unsigned q0 = (unsigned)__shfl((int)p[0], src, 64);
                    const unsigned q1 = (unsigned)__shfl((int)p[1], src, 64);
                    rk[0] += (q0 > p[0]) + (q1 > p[0]);
                    rk[1] += (q0 > p[1]) + (q1 > p[1]);
                }
            } else {
                for (int s = 0; s < 64; ++s) {
                    const int src = (lane + s) & 63;
#pragma unroll
                    for (int e = 0; e < 3; ++e) {
                        const unsigned q = (unsigned)__shfl((int)p[e], src, 64);
#pragma unroll
                        for (int a = 0; a < 3; ++a) rk[a] += (q > p[a]);
                    }
                }
            }
#pragma unroll
            for (int e = 0; e < 3; ++e) {
                if (e < S && rk[e] < 64) {
                    if (p[e] >= 8192u) {                        // real entry (val>thr -> big key)
                        ext_i[r * 64 + rk[e]] = (unsigned short)(8191 - (p[e] & 0x1fffu));
                        ext_v[r * 64 + rk[e]] = __uint_as_float((p[e] >> 13) << 16);
                    } else {                                    // filler: unique sentinel, val 0
                        ext_i[r * 64 + rk[e]] = (unsigned short)(0x2000 + rk[e]);
                        ext_v[r * 64 + rk[e]] = 0.0f;
                    }
                }
            }
        }
    }
    __syncthreads();

    // ---- Phase 3: exact serial-fmaf rescore of the boundary window only ----
    {
        const int r = tid & 63, c = tid >> 6;                   // 8 threads/row
        const float v32 = ext_v[r * 64 + TOPK - 1];             // approx 32nd value
        __syncthreads();                                        // all read v32 before any writes
        const float* xr = x + (size_t)(row0 + r) * D_IN;
        for (int j = c; j < 64; j += 8) {
            const float va = ext_v[r * 64 + j];
            const int   h  = ext_i[r * 64 + j];
            if (h < H_LAT && fabsf(va - v32) <= DELTA) {
                const float* wr_ = W_enc + (size_t)h * D_IN;
                float s = 0.0f;
                for (int kk = 0; kk < D_IN / 4; ++kk) {         // serial fmaf == np oracle
                    const float4 xv = ((const float4*)xr)[kk];
                    const float4 dv = ((const float4*)b_dec)[kk];
                    const float4 wv = ((const float4*)wr_)[kk];
                    s = fmaf(xv.x - dv.x, wv.x, s);
                    s = fmaf(xv.y - dv.y, wv.y, s);
                    s = fmaf(xv.z - dv.z, wv.z, s);
                    s = fmaf(xv.w - dv.w, wv.w, s);
                }
                ext_v[r * 64 + j] = fmaxf(s + b_enc[h], 0.0f);
            }
        }
    }
    __syncthreads();

    // ---- Phase 4: final rank -> top-32 -> bf16 decoder ----
    {
        const int rbase = wave * 8;
        const float4 bd4 = *(const float4*)&b_dec[lane * 4];
        for (int rr = 0; rr < 8; ++rr) {
            const int r = rbase + rr;
            const float v = ext_v[r * 64 + lane];
            const int   h = ext_i[r * 64 + lane];
            int rank = 0;
            for (int s = 0; s < 64; ++s) {
                const int src = (lane + s) & 63;
                const float wv = __shfl(v, src, 64);
                const int   wh = __shfl(h, src, 64);
                rank += (wv > v) || (wv == v && wh < h);        // val desc, idx asc; keys unique
            }
            if (rank < TOPK) { ext_v[r * 64 + rank] = v; ext_i[r * 64 + rank] = (unsigned short)h; }
            float4 o = bd4;                                     // wave-in-order: writes visible below
#pragma unroll 8
            for (int k = 0; k < TOPK; ++k) {
                const float vv = ext_v[r * 64 + k];             // LDS broadcast
                const int   hh = ext_i[r * 64 + k];
                if (hh < H_LAT) {                               // wave-uniform (guards sentinel)
                    const ushort4 w = *(const ushort4*)&Wdbf[(size_t)hh * D_IN + lane * 4];
                    o.x = fmaf(vv, bf2f(w.x), o.x); o.y = fmaf(vv, bf2f(w.y), o.y);
                    o.z = fmaf(vv, bf2f(w.z), o.z); o.w = fmaf(vv, bf2f(w.w), o.w);
                }
            }
            *(float4*)&out[(size_t)(row0 + r) * D_IN + lane * 4] = o;
        }
    }
}

extern "C" void kernel_launch(void* const* d_in, const int* in_sizes, int n_in,
                              void* d_out, int out_size, void* d_ws, size_t ws_size,
                              hipStream_t stream) {
    const float* x     = (const float*)d_in[0];
    const float* W_enc = (const float*)d_in[1];
    const float* b_enc = (const float*)d_in[2];
    const float* W_dec = (const float*)d_in[3];
    const float* b_dec = (const float*)d_in[4];
    float* out = (float*)d_out;

    const size_t wel = (size_t)H_LAT * D_IN;                    // 2M elements
    float* s2w = (float*)d_ws;                                  // 1 float @ offset 0
    unsigned short* Wbf  = (unsigned short*)((char*)d_ws + 256); // 4 MB bf16 W_enc
    unsigned short* Wdbf = Wbf + wel;                            // 4 MB bf16 W_dec

    hipMemsetAsync(d_ws, 0, 256, stream);                       // zero s2w (ws is poisoned)
    conv_kernel<<<dim3(1024), dim3(256), 0, stream>>>(W_enc, Wbf, s2w, W_dec, Wdbf);
    sae_main<<<dim3(B_TOK / MT), dim3(512), 0, stream>>>(x, W_enc, b_enc, W_dec, b_dec,
                                                         out, Wbf, s2w, Wdbf);
}